// Round 1
// 1244.147 us; speedup vs baseline: 1.1162x; 1.1162x over previous
//
#include <hip/hip_runtime.h>
#include <stdint.h>
#include <stddef.h>

// SimpleRNN: B=64, T=512, D_IN=256, H=1024, D_OUT=256 (fp32 in/out)
//
// SINGLE FUSED LAUNCH, 256 WGs x 256 thr (one per CU; __launch_bounds__(256,2)
// caps VGPR<=256 so every CU can host >=2 WGs -> all 256 WGs resident under
// any dispatch distribution -> no deadlock without cooperative launch).
//
//   WGs 0..63   : persistent scan (identical structure to the 1234us kernel).
//                 xp is now read via relaxed AGENT atomic loads + poison
//                 retry (producers run concurrently); the 2 loads issue at
//                 step top and are checked only at the epilogue, so their
//                 latency hides under the h-poll + MFMA.
//   WGs 64..255 : workers. Phase X = xproj (inputs@W_in+b, atomic stores so
//                 values land at the LLC coherence point, t-ascending job
//                 order, stays ~16x ahead of scan consumption). Phase O =
//                 outproj, trailing the scan frontier via data-as-flag polls
//                 with a 2-qword canary probe + s_sleep backoff (keeps worker
//                 poll traffic off the scan's latency-critical LLC path).
//
// Data-as-flag everywhere: harness poisons d_ws to 0xAA before every launch;
// a qword == 0xAAAAAAAAAAAAAAAA never occurs in legit xp (fp32 pairs) or
// hbuf (bf16x4) data.

#define TT 512
#define HH 1024

typedef __attribute__((ext_vector_type(8))) short short8;
typedef __attribute__((ext_vector_type(4))) float f32x4;
typedef unsigned long long u64;

#define POISON 0xAAAAAAAAAAAAAAAAull

// fp32 -> bf16 (round-to-nearest-even), bit pattern as short
__device__ __forceinline__ short f2bf(float f) {
  uint32_t u = __builtin_bit_cast(uint32_t, f);
  u += 0x7fffu + ((u >> 16) & 1u);
  return (short)(u >> 16);
}

__device__ __forceinline__ float fast_tanh(float x) {
  float ax = fabsf(x);
  float e = __expf(-2.f * ax);                       // e in (0,1]
  float r = (1.f - e) * __builtin_amdgcn_rcpf(1.f + e);
  return copysignf(r, x);
}

__device__ __forceinline__ u64 ald(const u64* p) {
  return __hip_atomic_load(p, __ATOMIC_RELAXED, __HIP_MEMORY_SCOPE_AGENT);
}
__device__ __forceinline__ void ast(u64* p, u64 v) {
  __hip_atomic_store(p, v, __ATOMIC_RELAXED, __HIP_MEMORY_SCOPE_AGENT);
}

// smem overlay:
//   scan    : red f32x4[4][4][64] (16384 B) + tr short[16][72] (2304 B)
//   worker X: ldsA short[16*264]  (8448 B)
//   worker O: red f32x4[4][4][64] (16384 B)
__global__ __launch_bounds__(256, 2) void rnn_fused(
    const float* __restrict__ inp, const float* __restrict__ w_in,
    const float* __restrict__ w_h, const float* __restrict__ h_b,
    const float* __restrict__ w_o, const float* __restrict__ o_b,
    float* __restrict__ xp, short* __restrict__ hbuf,
    float* __restrict__ out) {
  __shared__ __attribute__((aligned(16))) char smem[18688];
  const int blk = blockIdx.x;
  const int tid = threadIdx.x;
  const int wv = tid >> 6, l = tid & 63, lr = l & 15, lq = l >> 4;

  if (blk < 64) {
    // ------------------------------------------------------------------
    // SCAN: g = blk&3 (16-batch group), j = blk>>2 (64-col chunk).
    // ------------------------------------------------------------------
    const int g = blk & 3, j = blk >> 2;
    const int ntg = j * 4 + wv;  // this wave's n-tile for the epilogue

    f32x4 (*red)[4][64] = (f32x4 (*)[4][64])smem;
    short (*tr)[72] = (short (*)[72])(smem + 16384);

    // W_h B-fragments, register resident. wave wv: k in [wv*256, wv*256+256)
    short8 wf[8][4];
#pragma unroll
    for (int f = 0; f < 8; ++f)
#pragma unroll
      for (int nt = 0; nt < 4; ++nt) {
        int n = j * 64 + nt * 16 + lr;
        int k0 = wv * 256 + f * 32 + lq * 8;
        short8 v;
#pragma unroll
        for (int e = 0; e < 8; ++e) v[e] = f2bf(w_h[(size_t)(k0 + e) * HH + n]);
        wf[f][nt] = v;
      }

    const u64* hq = (const u64*)hbuf;
    u64* hqw = (u64*)hbuf;
    const u64* xq = (const u64*)xp;

    for (int t = 0; t < TT; ++t) {
      // xp prefetch: atomic (LLC) loads issued now, validated at epilogue.
      size_t xb = ((size_t)(t * 4 + g) * 64 + ntg) * 128 + (size_t)l * 2;
      u64 x0 = ald(xq + xb), x1 = ald(xq + xb + 1);

      f32x4 acc[4];
#pragma unroll
      for (int nt = 0; nt < 4; ++nt) acc[nt] = (f32x4){0.f, 0.f, 0.f, 0.f};

      if (t > 0) {
        // load this wave's K-chunk of h_{t-1}; data doubles as ready flag.
        u64 q[16];
        size_t base = (((size_t)((t - 1) * 4 + g) * 32 + wv * 8) * 64 + l) * 2;
        int bad;
        do {
#pragma unroll
          for (int f = 0; f < 8; ++f) {
            q[2 * f]     = ald(hq + base + (size_t)f * 128);
            q[2 * f + 1] = ald(hq + base + (size_t)f * 128 + 1);
          }
          int mybad = 0;
#pragma unroll
          for (int i = 0; i < 16; ++i) mybad |= (q[i] == POISON);
          bad = __any(mybad);
        } while (bad);

        short8 af[8];
#pragma unroll
        for (int f = 0; f < 8; ++f) {
          union { u64 qq[2]; short8 s; } u;
          u.qq[0] = q[2 * f];
          u.qq[1] = q[2 * f + 1];
          af[f] = u.s;
        }
#pragma unroll
        for (int f = 0; f < 8; ++f)
#pragma unroll
          for (int nt = 0; nt < 4; ++nt)
            acc[nt] = __builtin_amdgcn_mfma_f32_16x16x32_bf16(af[f], wf[f][nt], acc[nt], 0, 0, 0);
      }

      // cross-wave K reduction in LDS
      red[wv][0][l] = acc[0];
      red[wv][1][l] = acc[1];
      red[wv][2][l] = acc[2];
      red[wv][3][l] = acc[3];
      __syncthreads();  // B1
      f32x4 tot = red[0][wv][l] + red[1][wv][l] + red[2][wv][l] + red[3][wv][l];

      // xp validation (rare retry: only possible in the first few steps
      // while the workers' xproj frontier is still close)
      while (__any((x0 == POISON) | (x1 == POISON))) {
        x0 = ald(xq + xb);
        x1 = ald(xq + xb + 1);
      }
      union { u64 qq[2]; f32x4 v; } xu;
      xu.qq[0] = x0;
      xu.qq[1] = x1;

      // epilogue: + xp, tanh, bf16 into transpose buffer (C -> A layout)
#pragma unroll
      for (int i2 = 0; i2 < 4; ++i2) {
        float v = tot[i2] + xu.v[i2];
        tr[lq * 4 + i2][wv * 16 + lr] = f2bf(fast_tanh(v));
      }
      __syncthreads();  // B2

      // waves 0,1 emit the two A-frags for this WG's 64 cols (relaxed agent
      // atomics land at the LLC coherence point; consumers self-validate)
      if (wv < 2) {
        short8 hv = *(const short8*)&tr[lr][wv * 32 + lq * 8];
        union { short8 s; u64 qq[2]; } u;
        u.s = hv;
        size_t wbase = (((size_t)(t * 4 + g) * 32 + (j * 2 + wv)) * 64 + l) * 2;
        ast(hqw + wbase, u.qq[0]);
        ast(hqw + wbase + 1, u.qq[1]);
      }
    }
  } else {
    // ------------------------------------------------------------------
    // WORKER: w = blk-64 in [0,192). c = w&3 (col chunk), s48 = w>>2.
    // Job stream: m = s48 + 48*k, k < 43, m < 2048  (t ascending with k).
    // ------------------------------------------------------------------
    const int w = blk - 64;
    const int c = w & 3, s48 = w >> 2;

    {  // ---------------- phase X: xproj ----------------
      short* ldsA = (short*)smem;  // [16 rows][256 k] bf16, pitch 264

      short8 wfx[8][4];
#pragma unroll
      for (int kt = 0; kt < 8; ++kt)
#pragma unroll
        for (int nt = 0; nt < 4; ++nt) {
          int col = c * 256 + (wv * 4 + nt) * 16 + lr;
          int k0 = kt * 32 + lq * 8;
          short8 v;
#pragma unroll
          for (int e = 0; e < 8; ++e) v[e] = f2bf(w_in[(size_t)(k0 + e) * HH + col]);
          wfx[kt][nt] = v;
        }
      float bias[4];
#pragma unroll
      for (int nt = 0; nt < 4; ++nt) bias[nt] = h_b[c * 256 + (wv * 4 + nt) * 16 + lr];

      u64* xqw = (u64*)xp;
      for (int k = 0; k < 43; ++k) {
        int m = s48 + 48 * k;
        if (m >= 2048) break;
        int t = m >> 2, g2 = m & 3;
        {  // stage A tile: thread handles 16 consecutive floats of one row
          int row = tid >> 4, cb = (tid & 15) * 16;
          const float* src = inp + ((size_t)(g2 * 16 + row) * TT + t) * 256 + cb;
          f32x4 v0 = *(const f32x4*)(src);
          f32x4 v1 = *(const f32x4*)(src + 4);
          f32x4 v2 = *(const f32x4*)(src + 8);
          f32x4 v3 = *(const f32x4*)(src + 12);
          short8 sa, sb;
          sa[0]=f2bf(v0[0]); sa[1]=f2bf(v0[1]); sa[2]=f2bf(v0[2]); sa[3]=f2bf(v0[3]);
          sa[4]=f2bf(v1[0]); sa[5]=f2bf(v1[1]); sa[6]=f2bf(v1[2]); sa[7]=f2bf(v1[3]);
          sb[0]=f2bf(v2[0]); sb[1]=f2bf(v2[1]); sb[2]=f2bf(v2[2]); sb[3]=f2bf(v2[3]);
          sb[4]=f2bf(v3[0]); sb[5]=f2bf(v3[1]); sb[6]=f2bf(v3[2]); sb[7]=f2bf(v3[3]);
          *(short8*)&ldsA[row * 264 + cb] = sa;
          *(short8*)&ldsA[row * 264 + cb + 8] = sb;
        }
        __syncthreads();

        f32x4 acc[4];
#pragma unroll
        for (int nt = 0; nt < 4; ++nt) acc[nt] = (f32x4){0.f, 0.f, 0.f, 0.f};
#pragma unroll
        for (int kt = 0; kt < 8; ++kt) {
          short8 a = *(const short8*)&ldsA[lr * 264 + kt * 32 + lq * 8];
#pragma unroll
          for (int nt = 0; nt < 4; ++nt)
            acc[nt] = __builtin_amdgcn_mfma_f32_16x16x32_bf16(a, wfx[kt][nt], acc[nt], 0, 0, 0);
        }
        // atomic stores: xp must be visible to the scan's LLC atomic loads
#pragma unroll
        for (int nt = 0; nt < 4; ++nt) {
          union { f32x4 v; u64 qq[2]; } u;
#pragma unroll
          for (int i2 = 0; i2 < 4; ++i2) u.v[i2] = acc[nt][i2] + bias[nt];
          size_t base =
              ((size_t)(t * 4 + g2) * 64 + c * 16 + wv * 4 + nt) * 128 + (size_t)l * 2;
          ast(xqw + base, u.qq[0]);
          ast(xqw + base + 1, u.qq[1]);
        }
        __syncthreads();  // protect ldsA before next job
      }
    }

    {  // ---------------- phase O: outproj ----------------
      f32x4 (*red)[4][64] = (f32x4 (*)[4][64])smem;

      short8 wfo[8][4];
#pragma unroll
      for (int f = 0; f < 8; ++f)
#pragma unroll
        for (int nt = 0; nt < 4; ++nt) {
          int o = c * 64 + nt * 16 + lr;
          int k0 = wv * 256 + f * 32 + lq * 8;
          short8 v;
#pragma unroll
          for (int e = 0; e < 8; ++e) v[e] = f2bf(w_o[(size_t)(k0 + e) * 256 + o]);
          wfo[f][nt] = v;
        }
      float bias = o_b[c * 64 + wv * 16 + lr];
      const u64* hq = (const u64*)hbuf;

      for (int k = 0; k < 43; ++k) {
        int m = s48 + 48 * k;
        if (m >= 2048) break;
        int t = m >> 2, g2 = m & 3;

        u64 q[16];
        size_t base = (((size_t)(t * 4 + g2) * 32 + wv * 8) * 64 + l) * 2;
        // canary probe with s_sleep backoff (~0.85us) — workers wait here
        // most of the time; low-rate polling keeps the LLC path clear for
        // the scan's latency-critical loads.
        for (;;) {
          q[0] = ald(hq + base);
          q[1] = ald(hq + base + 1);
          if (!__any((q[0] == POISON) | (q[1] == POISON))) break;
          __builtin_amdgcn_s_sleep(32);
        }
        // remaining 7 frags: fast poll (producers of one step land within
        // a small straggler window)
        int bad;
        do {
#pragma unroll
          for (int f = 1; f < 8; ++f) {
            q[2 * f]     = ald(hq + base + (size_t)f * 128);
            q[2 * f + 1] = ald(hq + base + (size_t)f * 128 + 1);
          }
          int mybad = 0;
#pragma unroll
          for (int i = 2; i < 16; ++i) mybad |= (q[i] == POISON);
          bad = __any(mybad);
          if (bad) __builtin_amdgcn_s_sleep(8);
        } while (bad);

        short8 af[8];
#pragma unroll
        for (int f = 0; f < 8; ++f) {
          union { u64 qq[2]; short8 s; } u;
          u.qq[0] = q[2 * f];
          u.qq[1] = q[2 * f + 1];
          af[f] = u.s;
        }
        f32x4 acc[4];
#pragma unroll
        for (int nt = 0; nt < 4; ++nt) acc[nt] = (f32x4){0.f, 0.f, 0.f, 0.f};
#pragma unroll
        for (int f = 0; f < 8; ++f)
#pragma unroll
          for (int nt = 0; nt < 4; ++nt)
            acc[nt] = __builtin_amdgcn_mfma_f32_16x16x32_bf16(af[f], wfo[f][nt], acc[nt], 0, 0, 0);

        red[wv][0][l] = acc[0];
        red[wv][1][l] = acc[1];
        red[wv][2][l] = acc[2];
        red[wv][3][l] = acc[3];
        __syncthreads();
        f32x4 tot = red[0][wv][l] + red[1][wv][l] + red[2][wv][l] + red[3][wv][l];
#pragma unroll
        for (int i2 = 0; i2 < 4; ++i2) {
          int b = g2 * 16 + lq * 4 + i2;
          out[((size_t)b * TT + t) * 256 + c * 64 + wv * 16 + lr] = tot[i2] + bias;
        }
        __syncthreads();  // protect red before next job
      }
    }
  }
}

// ---------------------------------------------------------------------------
extern "C" void kernel_launch(void* const* d_in, const int* in_sizes, int n_in,
                              void* d_out, int out_size, void* d_ws, size_t ws_size,
                              hipStream_t stream) {
  const float* inp  = (const float*)d_in[0];
  const float* w_in = (const float*)d_in[1];
  const float* w_h  = (const float*)d_in[2];
  const float* h_b  = (const float*)d_in[3];
  const float* w_o  = (const float*)d_in[4];
  const float* o_b  = (const float*)d_in[5];

  // workspace layout (harness poisons d_ws to 0xAA before every launch —
  // both data-as-flag protocols depend on that)
  float* xp   = (float*)d_ws;                               // 128 MiB
  short* hbuf = (short*)((char*)d_ws + (size_t)134217728);  // 64 MiB

  rnn_fused<<<256, 256, 0, stream>>>(inp, w_in, w_h, h_b, w_o, o_b, xp, hbuf,
                                     (float*)d_out);
}